// Round 2
// 121.924 us; speedup vs baseline: 1.0241x; 1.0241x over previous
//
#include <hip/hip_runtime.h>

#define POOL 7
#define NUM_ROIS 300
#define H_IMG 200
#define W_IMG 200
#define C_IMG 512

// clang-native 16B vector for nontemporal builtins (HIP float4 is a class
// type the builtin rejects; this has identical layout).
typedef float f32x4 __attribute__((ext_vector_type(4)));

// One block per (roi, py, px). 128 threads x float4 = 512 channels.
// All ROI/cell index math is wave-uniform; channel loads are coalesced
// 16B/lane on the contiguous NHWC channel dim.
//
// R2 = R1 with the nontemporal store fixed to use a native vector type:
//  - skip corner loads whose bilinear weight is exactly 0 (fx==0 / fy==0:
//    px==0, py==0, and w%7==0 / h%7==0 ROIs where w/7.f is exact) or which
//    alias v00/v10 via boundary clamp (ix1==ix0 / iy1==iy0). Conditions are
//    block-uniform -> s_cbranch, no divergence. Bit-identical results:
//    ref multiplies finite values by exactly 0.0f in these cases.
//  - nontemporal store for the 30 MB streaming output (never re-read;
//    default WB stores evict ~an entire 4 MB L2 per XCD of image lines).
__global__ __launch_bounds__(128) void roi_pool_kernel(
    const float* __restrict__ img,
    const float* __restrict__ rois,
    float* __restrict__ out)
{
    const int b    = blockIdx.x;          // 0 .. 300*49-1
    const int roi  = b / (POOL * POOL);
    const int cell = b - roi * (POOL * POOL);
    const int py   = cell / POOL;
    const int px   = cell - py * POOL;

    // rois[roi] = (x, y, w, h) as float-encoded ints; one 16B load
    const float4 rv = *(const float4*)(rois + roi * 4);

    // reference: x0 = clip(int(x), 0, W-1); w = clip(max(int(w),1), 1, W-x0)
    const int x0 = min(max((int)rv.x, 0), W_IMG - 1);
    const int y0 = min(max((int)rv.y, 0), H_IMG - 1);
    const int w  = min(max((int)rv.z, 1), W_IMG - x0);
    const int h  = min(max((int)rv.w, 1), H_IMG - y0);

    // TF1 resize_images(align_corners=False): src = dst * (in/out)
    const float xs = (float)px * ((float)w / (float)POOL);
    const float ys = (float)py * ((float)h / (float)POOL);
    int ix0 = (int)floorf(xs);
    int iy0 = (int)floorf(ys);
    const float fx = xs - (float)ix0;   // computed BEFORE clamping ix0 (matches ref)
    const float fy = ys - (float)iy0;
    ix0 = min(ix0, w - 1);
    iy0 = min(iy0, h - 1);
    const int ix1 = min(ix0 + 1, w - 1);
    const int iy1 = min(iy0 + 1, h - 1);

    const int ax0 = x0 + ix0;
    const int ax1 = x0 + ix1;
    const int ay0 = y0 + iy0;
    const int ay1 = y0 + iy1;

    // Does the x1/y1 corner contribute anything v00/v10 doesn't already hold?
    //  - fx==0.0f exactly => weight of v01/v11 is exactly 0 (ref: finite*0.0f)
    //  - ix1==ix0 (clamp) => same pixel as v00/v10
    const bool needx = (fx != 0.0f) && (ix1 != ix0);
    const bool needy = (fy != 0.0f) && (iy1 != iy0);

    const int c = threadIdx.x * 4;      // 4 channels per thread

    const float4 v00 = *(const float4*)(img + ((size_t)(ay0 * W_IMG + ax0)) * C_IMG + c);
    float4 v01 = v00;
    float4 v10 = v00;
    float4 v11;
    if (needx)
        v01 = *(const float4*)(img + ((size_t)(ay0 * W_IMG + ax1)) * C_IMG + c);
    if (needy)
        v10 = *(const float4*)(img + ((size_t)(ay1 * W_IMG + ax0)) * C_IMG + c);
    if (needx && needy)
        v11 = *(const float4*)(img + ((size_t)(ay1 * W_IMG + ax1)) * C_IMG + c);
    else if (needx)
        v11 = v01;   // iy clamped or fy==0: row1 == row0 (or weight 0)
    else
        v11 = v10;   // ix clamped or fx==0: col1 == col0 (or weight 0)

    const float gx = 1.0f - fx;
    const float gy = 1.0f - fy;

    f32x4 o;
    o.x = (v00.x * gx + v01.x * fx) * gy + (v10.x * gx + v11.x * fx) * fy;
    o.y = (v00.y * gx + v01.y * fx) * gy + (v10.y * gx + v11.y * fx) * fy;
    o.z = (v00.z * gx + v01.z * fx) * gy + (v10.z * gx + v11.z * fx) * fy;
    o.w = (v00.w * gx + v01.w * fx) * gy + (v10.w * gx + v11.w * fx) * fy;

    float* dst = out + ((size_t)((roi * POOL + py) * POOL + px)) * C_IMG + c;
    __builtin_nontemporal_store(o, (f32x4*)dst);
}

extern "C" void kernel_launch(void* const* d_in, const int* in_sizes, int n_in,
                              void* d_out, int out_size, void* d_ws, size_t ws_size,
                              hipStream_t stream) {
    const float* img  = (const float*)d_in[0];   // (1,200,200,512) fp32
    const float* rois = (const float*)d_in[1];   // (1,300,4) fp32
    float* out = (float*)d_out;                  // (1,300,7,7,512) fp32

    const int nblocks = NUM_ROIS * POOL * POOL;  // 14700
    roi_pool_kernel<<<nblocks, 128, 0, stream>>>(img, rois, out);
}